// Round 5
// baseline (206.918 us; speedup 1.0000x reference)
//
#include <hip/hip_runtime.h>
#include <stdint.h>

#define B_ 32
#define E_ 256
#define L_ 2048
#define D_ 256
#define KS 4
#define KCHUNK (L_ / KS)      // 512
#define NKT (KCHUNK / 32)     // 16 k-steps of 32

typedef __attribute__((ext_vector_type(4))) float  f32x4;
typedef __attribute__((ext_vector_type(8))) short  s16x8;

// fp32 -> (hi, lo) bf16 pair. hi = truncated bf16(x); lo = bf16(x - hi).
__device__ __forceinline__ void cvt_hilo1(float x, short &h, short &l) {
    unsigned u = __builtin_bit_cast(unsigned, x);
    h = (short)(u >> 16);
    float hf = __builtin_bit_cast(float, u & 0xFFFF0000u);
    unsigned r = __builtin_bit_cast(unsigned, x - hf);
    l = (short)(r >> 16);
}

__global__ void zero_out_kernel(f32x4* __restrict__ out) {
    out[(size_t)blockIdx.x * 256 + threadIdx.x] = f32x4{0.f, 0.f, 0.f, 0.f};
}

// No LDS, no barriers: each wave owns a 32e x 64d x 512k task and loads both
// MFMA operands directly from global in fragment layout.
//   A (emap) k-contiguous: lane(ml,kg) -> rows e0+mi*16+ml, k=kg*8..+7 (2x dwordx4)
//   B (doc)  d-contiguous: lane(ml,kg) -> k=kg*8+j (stride D), d=d0+ni*16+ml (8x dword)
__global__ __launch_bounds__(256, 3)
void mean_pool_kernel(const float* __restrict__ doc,
                      const float* __restrict__ emap,
                      const float* __restrict__ lens,
                      float* __restrict__ out) {
    const int t    = threadIdx.x;
    const int lane = t & 63;
    const int gw   = blockIdx.x * 4 + (t >> 6);   // 4096 waves
    const int ks   = gw & 3;                      // k-split chunk
    const int dt   = (gw >> 2) & 3;               // d-tile (64 wide)
    const int e8   = (gw >> 4) & 7;               // e-tile (32 tall)
    const int b    = gw >> 7;                     // batch
    const int d0   = dt * 64;
    const int e0   = e8 * 32;
    const int ml   = lane & 15;
    const int kg   = lane >> 4;                   // 0..3

    const float* Ab = emap + ((size_t)(b * E_ + e0 + ml)) * L_ + ks * KCHUNK + kg * 8;
    const float* Bb = doc  + ((size_t)(b * L_ + ks * KCHUNK + kg * 8)) * D_ + d0 + ml;

    f32x4 av[2][2][2];   // [buf][mi][half]  A fp32 fragments
    float bv[2][4][8];   // [buf][ni][j]     B fp32 fragments
    f32x4 acc[2][4] = {};

    // preload k-step 0 into buffer 0
    #pragma unroll
    for (int mi = 0; mi < 2; ++mi) {
        av[0][mi][0] = *(const f32x4*)(Ab + (size_t)mi * 16 * L_);
        av[0][mi][1] = *(const f32x4*)(Ab + (size_t)mi * 16 * L_ + 4);
    }
    #pragma unroll
    for (int ni = 0; ni < 4; ++ni)
        #pragma unroll
        for (int j = 0; j < 8; ++j)
            bv[0][ni][j] = Bb[(size_t)j * D_ + ni * 16];

    #pragma unroll 2
    for (int kt = 0; kt < NKT; ++kt) {
        const int cur = kt & 1, nxt = cur ^ 1;

        // issue next k-step's global loads (fire-and-forget; no barrier ever drains them)
        if (kt + 1 < NKT) {
            const int kc = (kt + 1) * 32;
            #pragma unroll
            for (int mi = 0; mi < 2; ++mi) {
                av[nxt][mi][0] = *(const f32x4*)(Ab + (size_t)mi * 16 * L_ + kc);
                av[nxt][mi][1] = *(const f32x4*)(Ab + (size_t)mi * 16 * L_ + kc + 4);
            }
            #pragma unroll
            for (int ni = 0; ni < 4; ++ni)
                #pragma unroll
                for (int j = 0; j < 8; ++j)
                    bv[nxt][ni][j] = Bb[(size_t)(kc + j) * D_ + ni * 16];
        }

        // convert current fragments to hi/lo bf16
        s16x8 ah[2], al[2];
        #pragma unroll
        for (int mi = 0; mi < 2; ++mi)
            #pragma unroll
            for (int ii = 0; ii < 8; ++ii) {
                short hh, ll;
                cvt_hilo1(av[cur][mi][ii >> 2][ii & 3], hh, ll);
                ah[mi][ii] = hh; al[mi][ii] = ll;
            }
        s16x8 bh[4], bl[4];
        #pragma unroll
        for (int ni = 0; ni < 4; ++ni)
            #pragma unroll
            for (int j = 0; j < 8; ++j) {
                short hh, ll;
                cvt_hilo1(bv[cur][ni][j], hh, ll);
                bh[ni][j] = hh; bl[ni][j] = ll;
            }

        // 3-pass hi/lo MFMA
        #pragma unroll
        for (int mi = 0; mi < 2; ++mi)
            #pragma unroll
            for (int ni = 0; ni < 4; ++ni) {
                acc[mi][ni] = __builtin_amdgcn_mfma_f32_16x16x32_bf16(ah[mi], bh[ni], acc[mi][ni], 0, 0, 0);
                acc[mi][ni] = __builtin_amdgcn_mfma_f32_16x16x32_bf16(ah[mi], bl[ni], acc[mi][ni], 0, 0, 0);
                acc[mi][ni] = __builtin_amdgcn_mfma_f32_16x16x32_bf16(al[mi], bh[ni], acc[mi][ni], 0, 0, 0);
            }
    }

    // epilogue: divide by entity_lens, atomically accumulate k-split partials
    #pragma unroll
    for (int mi = 0; mi < 2; ++mi)
        #pragma unroll
        for (int rr = 0; rr < 4; ++rr) {
            const int er = e0 + mi * 16 + kg * 4 + rr;
            const float lv = lens[b * E_ + er];
            #pragma unroll
            for (int ni = 0; ni < 4; ++ni)
                atomicAdd(&out[((size_t)(b * E_ + er)) * D_ + d0 + ni * 16 + ml],
                          acc[mi][ni][rr] / lv);
        }
}

extern "C" void kernel_launch(void* const* d_in, const int* in_sizes, int n_in,
                              void* d_out, int out_size, void* d_ws, size_t ws_size,
                              hipStream_t stream) {
    const float* doc  = (const float*)d_in[0];   // [32][2048][256]
    const float* emap = (const float*)d_in[1];   // [32][256][2048]
    const float* lens = (const float*)d_in[2];   // [32][256]
    float* out = (float*)d_out;                  // [32][256][256]

    // zero the output (harness poisons it with 0xAA), then accumulate partials
    zero_out_kernel<<<dim3(out_size / (4 * 256)), dim3(256), 0, stream>>>((f32x4*)out);

    dim3 grid(1024);   // 4096 waves: 4 ks x 4 dt x 8 e x 32 b
    dim3 block(256);
    hipLaunchKernelGGL(mean_pool_kernel, grid, block, 0, stream,
                       doc, emap, lens, out);
}

// Round 6
// 173.671 us; speedup vs baseline: 1.1914x; 1.1914x over previous
//
#include <hip/hip_runtime.h>
#include <stdint.h>

#define B_ 32
#define E_ 256
#define L_ 2048
#define D_ 256

#define BE 128
#define BD 128
#define BK 32
#define KS 4                  // k-split factor
#define KCHUNK (L_ / KS)      // 512
#define NKT (KCHUNK / BK)     // 16 k-tiles per block

typedef __attribute__((ext_vector_type(4))) float  f32x4;
typedef __attribute__((ext_vector_type(4))) short  s16x4;
typedef __attribute__((ext_vector_type(8))) short  s16x8;

// fp32 -> (hi, lo) bf16 pair. hi = truncated bf16(x); lo = bf16(x - hi).
__device__ __forceinline__ void cvt_hilo1(float x, short &h, short &l) {
    unsigned u = __builtin_bit_cast(unsigned, x);
    h = (short)(u >> 16);
    float hf = __builtin_bit_cast(float, u & 0xFFFF0000u);
    unsigned r = __builtin_bit_cast(unsigned, x - hf);
    l = (short)(r >> 16);
}

__global__ void zero_out_kernel(f32x4* __restrict__ out) {
    out[(size_t)blockIdx.x * 256 + threadIdx.x] = f32x4{0.f, 0.f, 0.f, 0.f};
}

// 128x128x32 tile, 256 threads = 4 waves as 2(e) x 2(d), wave tile 64x64.
// 48 MFMA per wave-iter vs 16 LDS b128 reads -> 2.05 B/MAC LDS intensity
// (R3 was 4.1) and half the barriers per CU. Staging/swizzle patterns are
// R3-verbatim (measured ~0-2M conflicts).
__global__ __launch_bounds__(256, 2)
void mean_pool_kernel(const float* __restrict__ doc,
                      const float* __restrict__ emap,
                      const float* __restrict__ lens,
                      float* __restrict__ out) {
    // A swizzle key: row&3.  B swizzle key: (row>>1)&3.
    __shared__ __align__(16) short As_hi[BE][BK];
    __shared__ __align__(16) short As_lo[BE][BK];
    __shared__ __align__(16) short Bs_hi[BD][BK];   // doc^T tile: [d][k]
    __shared__ __align__(16) short Bs_lo[BD][BK];
    __shared__ float lens_s[BE];

    const int t   = threadIdx.x;
    const int blk = blockIdx.x;
    const int ks  = blk & 3;
    const int d0  = ((blk >> 2) & 1) * BD;
    const int e0  = ((blk >> 3) & 1) * BE;
    const int b   = blk >> 4;

    const float* Ag = emap + ((size_t)b * E_ + e0) * L_ + ks * KCHUNK;
    const float* Sg = doc  + (size_t)b * L_ * D_ + (size_t)ks * KCHUNK * D_ + d0;

    if (t < BE) lens_s[t] = lens[b * E_ + e0 + t];

    // A staging: 4 float4 per thread: row = (t>>3) + rr*32, k = (t&7)*4
    const int a_c4 = t & 7;
    const int a_r  = t >> 3;            // 0..31
    // B staging: d = t&127, k-groups g = (t>>7) + rr*2 (rr=0,1), 8 floats each
    const int b_d  = t & 127;
    const int b_g0 = t >> 7;            // 0..1

    // wave coords: 4 waves as 2(e) x 2(d), wave tile 64e x 64d
    const int lane = t & 63;
    const int w    = t >> 6;
    const int eo   = (w & 1) * 64;
    const int dq   = (w >> 1) * 64;
    const int ml   = lane & 15;
    const int kg   = lane >> 4;         // 0..3

    f32x4 acc[4][4] = {};
    f32x4 pa[4];
    float pb[2][8];

    // preload tile 0
    #pragma unroll
    for (int rr = 0; rr < 4; ++rr)
        pa[rr] = *(const f32x4*)(Ag + (size_t)(a_r + rr * 32) * L_ + a_c4 * 4);
    #pragma unroll
    for (int rr = 0; rr < 2; ++rr)
        #pragma unroll
        for (int j = 0; j < 8; ++j)
            pb[rr][j] = Sg[(size_t)((b_g0 + rr * 2) * 8 + j) * D_ + b_d];

    for (int kt = 0; kt < NKT; ++kt) {
        // ---- convert & stage to LDS ----
        #pragma unroll
        for (int rr = 0; rr < 4; ++rr) {
            const int row = a_r + rr * 32;
            s16x4 h, l;
            #pragma unroll
            for (int i = 0; i < 4; ++i) { short hh, ll; cvt_hilo1(pa[rr][i], hh, ll); h[i] = hh; l[i] = ll; }
            const int col = (((a_c4 >> 1) ^ (row & 3)) << 3) + (a_c4 & 1) * 4;
            *(s16x4*)&As_hi[row][col] = h;
            *(s16x4*)&As_lo[row][col] = l;
        }
        #pragma unroll
        for (int rr = 0; rr < 2; ++rr) {
            const int g = b_g0 + rr * 2;
            s16x8 h, l;
            #pragma unroll
            for (int j = 0; j < 8; ++j) {
                short hh, ll; cvt_hilo1(pb[rr][j], hh, ll);
                h[j] = hh; l[j] = ll;
            }
            const int col = (g ^ ((b_d >> 1) & 3)) << 3;
            *(s16x8*)&Bs_hi[b_d][col] = h;
            *(s16x8*)&Bs_lo[b_d][col] = l;
        }
        __syncthreads();

        // ---- prefetch next tile's globals (completes during MFMA phase) ----
        if (kt + 1 < NKT) {
            const int k0 = (kt + 1) * BK;
            #pragma unroll
            for (int rr = 0; rr < 4; ++rr)
                pa[rr] = *(const f32x4*)(Ag + (size_t)(a_r + rr * 32) * L_ + k0 + a_c4 * 4);
            #pragma unroll
            for (int rr = 0; rr < 2; ++rr)
                #pragma unroll
                for (int j = 0; j < 8; ++j)
                    pb[rr][j] = Sg[(size_t)(k0 + (b_g0 + rr * 2) * 8 + j) * D_ + b_d];
        }

        // ---- fragment reads + MFMA: 3-pass hi/lo split, 4x4 accs ----
        {
            s16x8 ah[4], al[4], bh[4], bl[4];
            #pragma unroll
            for (int mi = 0; mi < 4; ++mi) {
                const int row = eo + mi * 16 + ml;
                const int col = (kg ^ (row & 3)) << 3;
                ah[mi] = *(const s16x8*)&As_hi[row][col];
                al[mi] = *(const s16x8*)&As_lo[row][col];
            }
            #pragma unroll
            for (int ni = 0; ni < 4; ++ni) {
                const int row = dq + ni * 16 + ml;
                const int col = (kg ^ ((row >> 1) & 3)) << 3;
                bh[ni] = *(const s16x8*)&Bs_hi[row][col];
                bl[ni] = *(const s16x8*)&Bs_lo[row][col];
            }
            #pragma unroll
            for (int mi = 0; mi < 4; ++mi)
                #pragma unroll
                for (int ni = 0; ni < 4; ++ni) {
                    acc[mi][ni] = __builtin_amdgcn_mfma_f32_16x16x32_bf16(ah[mi], bh[ni], acc[mi][ni], 0, 0, 0);
                    acc[mi][ni] = __builtin_amdgcn_mfma_f32_16x16x32_bf16(ah[mi], bl[ni], acc[mi][ni], 0, 0, 0);
                    acc[mi][ni] = __builtin_amdgcn_mfma_f32_16x16x32_bf16(al[mi], bh[ni], acc[mi][ni], 0, 0, 0);
                }
        }
        __syncthreads();
    }

    // ---- epilogue: divide by entity_lens, atomically accumulate k-split partials ----
    #pragma unroll
    for (int mi = 0; mi < 4; ++mi) {
        #pragma unroll
        for (int rr = 0; rr < 4; ++rr) {
            const int er = eo + mi * 16 + kg * 4 + rr;
            const float lv = lens_s[er];
            #pragma unroll
            for (int ni = 0; ni < 4; ++ni) {
                atomicAdd(&out[((size_t)(b * E_ + e0 + er)) * D_ + d0 + dq + ni * 16 + ml],
                          acc[mi][ni][rr] / lv);
            }
        }
    }
}

extern "C" void kernel_launch(void* const* d_in, const int* in_sizes, int n_in,
                              void* d_out, int out_size, void* d_ws, size_t ws_size,
                              hipStream_t stream) {
    const float* doc  = (const float*)d_in[0];   // [32][2048][256]
    const float* emap = (const float*)d_in[1];   // [32][256][2048]
    const float* lens = (const float*)d_in[2];   // [32][256]
    float* out = (float*)d_out;                  // [32][256][256]

    // zero the output (harness poisons it with 0xAA), then accumulate partials
    zero_out_kernel<<<dim3(out_size / (4 * 256)), dim3(256), 0, stream>>>((f32x4*)out);

    dim3 grid(B_ * (E_ / BE) * (D_ / BD) * KS);  // 512 workgroups = 2/CU
    dim3 block(256);
    hipLaunchKernelGGL(mean_pool_kernel, grid, block, 0, stream,
                       doc, emap, lens, out);
}